// Round 5
// baseline (692.625 us; speedup 1.0000x reference)
//
#include <hip/hip_runtime.h>

typedef _Float16 f16;
typedef _Float16 f16x8 __attribute__((ext_vector_type(8)));
typedef _Float16 f16x4 __attribute__((ext_vector_type(4)));
typedef float f32x4 __attribute__((ext_vector_type(4)));

#define NTOK 49
#define NH 16
#define HD 32
#define DIM 512
#define NWIN 64
#define NB 2048
#define MTOT (NB*NTOK)      // 100352
#define SCALE 0.17677669529663687f
#define VTS 56              // vt t-stride (padded, 16B-aligned rows)

__device__ __forceinline__ void gload_lds16(const f16* g, f16* l) {
    __builtin_amdgcn_global_load_lds((const __attribute__((address_space(1))) void*)g,
                                     (__attribute__((address_space(3))) void*)l, 16, 0, 0);
}

// ---------------- convert fp32 -> fp16 (vectorized) ----------------
__global__ __launch_bounds__(256) void cvt_f32_f16(const float* __restrict__ s,
                                                   f16* __restrict__ d, int n4) {
    int i = blockIdx.x * 256 + threadIdx.x;
    int st = gridDim.x * 256;
    for (; i < n4; i += st) {
        float4 v = ((const float4*)s)[i];
        f16x4 o = { (f16)v.x, (f16)v.y, (f16)v.z, (f16)v.w };
        *(f16x4*)(d + (size_t)i * 4) = o;
    }
}

// ------- bias+mask in MFMA-fragment layout: comb2[w][h][lane][ti*4+tj][r] f32 -------
__global__ __launch_bounds__(256) void build_comb2(const float* __restrict__ rpb,
                                                   const float* __restrict__ mask,
                                                   float* __restrict__ comb2) {
    int idx = blockIdx.x * 256 + threadIdx.x;   // total = 1024 * 64 * 64
    int r4   = idx & 3;
    int tj   = (idx >> 2) & 3;
    int ti   = (idx >> 4) & 3;
    int lane = (idx >> 6) & 63;
    int wh   = idx >> 12;           // w*16 + h
    int h = wh & 15, w = wh >> 4;
    int g = lane >> 4, c16 = lane & 15;
    int row = ti * 16 + g * 4 + r4;
    int col = tj * 16 + c16;
    float v = 0.f;
    if (row < NTOK && col < NTOK) {
        int ri = row / 7, ci = row - ri * 7;
        int rj = col / 7, cj = col - rj * 7;
        int rel = (ri - rj + 6) * 13 + (ci - cj + 6);
        v = rpb[rel * NH + h] + mask[(w * NTOK + row) * NTOK + col];
    }
    comb2[idx] = v;
}

// ---------------- 256x256 phase-pipelined GEMM (m201-style) ----------------
// C[m][n] = sum_k A[m][k]*B[n][k] + bias[n]
// 8 waves (2Mx4N), per-wave 128x64, BK=64, LDS 128KB double-buffered K-tiles.
// Per K-tile: 4 phases {ds_read | gload_lds prefetch | s_barrier | setprio+16 MFMA | s_barrier};
// register retention (af0/af1/bf0/bf1) keeps frag re-reads minimal; one vmcnt(0)/K-tile.
// Source-side XOR swizzle (rule 21): LDS[row][c] = global[row][c ^ (row&7)]; reads undo it.
// MODE 0: scatter q(*scale), k as [bid][t][d]; v transposed as [bid][d][VTS]
// MODE 1: fp32 out[m*512+n]
template<int MODE, int NT>   // NT = N/256 tiles
__global__ __launch_bounds__(512, 2) void gemm256(const f16* __restrict__ A,
                                                  const f16* __restrict__ Bw,
                                                  const float* __restrict__ bias,
                                                  f16* __restrict__ qo,
                                                  f16* __restrict__ ko,
                                                  f16* __restrict__ vto,
                                                  float* __restrict__ outp) {
    __shared__ __align__(16) f16 As[2][256][64];
    __shared__ __align__(16) f16 Bs[2][256][64];

    const int tid = threadIdx.x;
    const int lane = tid & 63;
    const int wv = tid >> 6;                // 0..7
    const int wm = wv >> 2, wn = wv & 3;    // 2 x 4 wave grid
    const int g = lane >> 4, c16 = lane & 15;
    const int sl8 = lane >> 3;              // staging row-within-8
    const int sc8 = (lane & 7) ^ sl8;       // swizzled source chunk

    // T1: bijective XCD-chunked remap (grid divisible by 8)
    const int nblk = gridDim.x;
    const int f = blockIdx.x;
    const int work = (f & 7) * (nblk >> 3) + (f >> 3);
    const int m0 = (work / NT) * 256;
    const int n0 = (work % NT) * 256;

    // staging source bases (per-lane swizzled col; LDS dest stays wave-uniform linear)
    const f16* gA0 = A  + (size_t)(m0 + wv * 8 + sl8) * DIM + sc8 * 8;
    const f16* gB0 = Bw + (size_t)(n0 + wv * 8 + sl8) * DIM + sc8 * 8;

#define STAGE(buf, kof, rd) \
    gload_lds16(gA0 + (size_t)((rd) * 64) * DIM + (kof), &As[buf][(rd) * 64 + wv * 8][0]); \
    gload_lds16(gB0 + (size_t)((rd) * 64) * DIM + (kof), &Bs[buf][(rd) * 64 + wv * 8][0]);

#define ARD(half, t2, kk) (*(const f16x8*)&As[pb][wm * 128 + (half) * 64 + (t2) * 16 + c16][((((kk) * 4 + g)) ^ (c16 & 7)) * 8])
#define BRD(half, j2, kk) (*(const f16x8*)&Bs[pb][wn * 64 + (half) * 32 + (j2) * 16 + c16][((((kk) * 4 + g)) ^ (c16 & 7)) * 8])

    f32x4 acc[8][4];
#pragma unroll
    for (int i = 0; i < 8; ++i)
#pragma unroll
        for (int j = 0; j < 4; ++j)
            acc[i][j] = (f32x4){0.f, 0.f, 0.f, 0.f};

    // prologue: stage K-tile 0 into buf 0
#pragma unroll
    for (int rd = 0; rd < 4; ++rd) { STAGE(0, 0, rd) }
    asm volatile("s_waitcnt vmcnt(0)" ::: "memory");
    __builtin_amdgcn_s_barrier();

    const int KT = DIM / 64;   // 8 K-tiles
    for (int t = 0; t < KT; ++t) {
        const int pb = t & 1, nb = pb ^ 1;
        const int kn = (t + 1) * 64;
        const bool hasn = (t + 1 < KT);
        f16x8 af0[4][2], af1[4][2], bf0[2][2], bf1[2][2];

        // ---- phase 0: quadrant (row-half 0, col-half 0) ----
#pragma unroll
        for (int t2 = 0; t2 < 4; ++t2)
#pragma unroll
            for (int kk = 0; kk < 2; ++kk) af0[t2][kk] = ARD(0, t2, kk);
#pragma unroll
        for (int j2 = 0; j2 < 2; ++j2)
#pragma unroll
            for (int kk = 0; kk < 2; ++kk) bf0[j2][kk] = BRD(0, j2, kk);
        if (hasn) { STAGE(nb, kn, 0) STAGE(nb, kn, 1) }
        __builtin_amdgcn_s_barrier();
        __builtin_amdgcn_s_setprio(1);
#pragma unroll
        for (int t2 = 0; t2 < 4; ++t2)
#pragma unroll
            for (int j2 = 0; j2 < 2; ++j2)
#pragma unroll
                for (int kk = 0; kk < 2; ++kk)
                    acc[t2][j2] = __builtin_amdgcn_mfma_f32_16x16x32_f16(af0[t2][kk], bf0[j2][kk], acc[t2][j2], 0, 0, 0);
        __builtin_amdgcn_s_setprio(0);
        __builtin_amdgcn_s_barrier();

        // ---- phase 1: quadrant (0, 1) — af0 retained, read bf1 ----
#pragma unroll
        for (int j2 = 0; j2 < 2; ++j2)
#pragma unroll
            for (int kk = 0; kk < 2; ++kk) bf1[j2][kk] = BRD(1, j2, kk);
        if (hasn) { STAGE(nb, kn, 2) STAGE(nb, kn, 3) }
        __builtin_amdgcn_s_barrier();
        __builtin_amdgcn_s_setprio(1);
#pragma unroll
        for (int t2 = 0; t2 < 4; ++t2)
#pragma unroll
            for (int j2 = 0; j2 < 2; ++j2)
#pragma unroll
                for (int kk = 0; kk < 2; ++kk)
                    acc[t2][2 + j2] = __builtin_amdgcn_mfma_f32_16x16x32_f16(af0[t2][kk], bf1[j2][kk], acc[t2][2 + j2], 0, 0, 0);
        __builtin_amdgcn_s_setprio(0);
        __builtin_amdgcn_s_barrier();

        // ---- phase 2: quadrant (1, 0) — bf0 retained, read af1 ----
#pragma unroll
        for (int t2 = 0; t2 < 4; ++t2)
#pragma unroll
            for (int kk = 0; kk < 2; ++kk) af1[t2][kk] = ARD(1, t2, kk);
        __builtin_amdgcn_s_barrier();
        __builtin_amdgcn_s_setprio(1);
#pragma unroll
        for (int t2 = 0; t2 < 4; ++t2)
#pragma unroll
            for (int j2 = 0; j2 < 2; ++j2)
#pragma unroll
                for (int kk = 0; kk < 2; ++kk)
                    acc[4 + t2][j2] = __builtin_amdgcn_mfma_f32_16x16x32_f16(af1[t2][kk], bf0[j2][kk], acc[4 + t2][j2], 0, 0, 0);
        __builtin_amdgcn_s_setprio(0);
        __builtin_amdgcn_s_barrier();

        // ---- phase 3: quadrant (1, 1) — all retained; drain staging once per K-tile ----
        __builtin_amdgcn_s_setprio(1);
#pragma unroll
        for (int t2 = 0; t2 < 4; ++t2)
#pragma unroll
            for (int j2 = 0; j2 < 2; ++j2)
#pragma unroll
                for (int kk = 0; kk < 2; ++kk)
                    acc[4 + t2][2 + j2] = __builtin_amdgcn_mfma_f32_16x16x32_f16(af1[t2][kk], bf1[j2][kk], acc[4 + t2][2 + j2], 0, 0, 0);
        __builtin_amdgcn_s_setprio(0);
        if (hasn) asm volatile("s_waitcnt vmcnt(0)" ::: "memory");
        __builtin_amdgcn_s_barrier();
    }
#undef STAGE
#undef ARD
#undef BRD

    // epilogue: C frag layout col = lane&15, row = (lane>>4)*4 + reg
#pragma unroll
    for (int i = 0; i < 8; ++i)
#pragma unroll
        for (int r = 0; r < 4; ++r) {
            int m = m0 + wm * 128 + i * 16 + g * 4 + r;
            int b = 0, t = 0;
            if (MODE == 0) { b = m / NTOK; t = m - b * NTOK; }
#pragma unroll
            for (int j = 0; j < 4; ++j) {
                int n = n0 + wn * 64 + j * 16 + c16;
                float v = acc[i][j][r] + bias[n];
                if (MODE == 0) {
                    int s = n >> 9;
                    int hh = (n >> 5) & 15;
                    int d = n & 31;
                    int bh = b * NH + hh;
                    if (s == 0)      qo[((size_t)bh * NTOK + t) * HD + d] = (f16)(v * SCALE);
                    else if (s == 1) ko[((size_t)bh * NTOK + t) * HD + d] = (f16)v;
                    else             vto[((size_t)bh * HD + d) * VTS + t] = (f16)v;
                } else {
                    outp[(size_t)m * DIM + n] = v;
                }
            }
        }
}

// ---------------- fused window attention: 4 waves/block, 1 wave per (b,h) ----------------
__global__ __launch_bounds__(256) void attn_kernel(const f16* __restrict__ qw,
                                                   const f16* __restrict__ kw,
                                                   const f16* __restrict__ vt,
                                                   const float* __restrict__ comb2,
                                                   f16* __restrict__ aout) {
    __shared__ __align__(16) f16 Ps[4][64][72];

    const int wv = threadIdx.x >> 6;
    const int l = threadIdx.x & 63;
    const int f = blockIdx.x;
    const int work = (f & 7) * (gridDim.x >> 3) + (f >> 3);
    const int bid = work * 4 + wv;
    const int b = bid >> 4, h = bid & 15;
    const int w = b & (NWIN - 1);
    const int g = l >> 4, c16 = l & 15;
    const size_t qkbase = (size_t)bid * (NTOK * HD);
    const size_t vbase = (size_t)bid * (HD * VTS);

    const f16x8 z8 = {};

    f16x8 qf[4], kf[4];
#pragma unroll
    for (int t = 0; t < 4; ++t) {
        int row = t * 16 + c16;
        f16x8 q = z8, k = z8;
        if (row < NTOK) {
            q = *(const f16x8*)(qw + qkbase + row * HD + g * 8);
            k = *(const f16x8*)(kw + qkbase + row * HD + g * 8);
        }
        qf[t] = q; kf[t] = k;
    }

    const float* cb = comb2 + (((size_t)(w * NH + h) * 64 + l) << 6);
    f32x4 S[4][4];
#pragma unroll
    for (int i = 0; i < 4; ++i)
#pragma unroll
        for (int j = 0; j < 4; ++j)
            S[i][j] = *(const f32x4*)(cb + (i * 4 + j) * 4);
#pragma unroll
    for (int i = 0; i < 4; ++i)
#pragma unroll
        for (int j = 0; j < 4; ++j)
            S[i][j] = __builtin_amdgcn_mfma_f32_16x16x32_f16(qf[i], kf[j], S[i][j], 0, 0, 0);

#pragma unroll
    for (int ti = 0; ti < 4; ++ti)
#pragma unroll
        for (int r = 0; r < 4; ++r) {
            int row = ti * 16 + g * 4 + r;
            float v0 = S[ti][0][r], v1 = S[ti][1][r], v2 = S[ti][2][r];
            float v3 = (c16 == 0) ? S[ti][3][r] : -1e30f;
            float mx = fmaxf(fmaxf(v0, v1), fmaxf(v2, v3));
#pragma unroll
            for (int mk = 1; mk < 16; mk <<= 1) mx = fmaxf(mx, __shfl_xor(mx, mk, 64));
            float p0 = __expf(v0 - mx), p1 = __expf(v1 - mx), p2 = __expf(v2 - mx);
            float p3 = (c16 == 0) ? __expf(v3 - mx) : 0.f;
            float sm = p0 + p1 + p2 + p3;
#pragma unroll
            for (int mk = 1; mk < 16; mk <<= 1) sm += __shfl_xor(sm, mk, 64);
            float inv = 1.f / sm;
            Ps[wv][row][c16]      = (f16)(p0 * inv);
            Ps[wv][row][16 + c16] = (f16)(p1 * inv);
            Ps[wv][row][32 + c16] = (f16)(p2 * inv);
            Ps[wv][row][48 + c16] = (f16)(p3 * inv);
        }
    __syncthreads();

    f32x4 O[4][2];
    const f32x4 zf = (f32x4){0.f, 0.f, 0.f, 0.f};
#pragma unroll
    for (int i = 0; i < 4; ++i) { O[i][0] = zf; O[i][1] = zf; }
#pragma unroll
    for (int c = 0; c < 2; ++c) {
        f16x8 pf[4], vf[2];
#pragma unroll
        for (int ti = 0; ti < 4; ++ti)
            pf[ti] = *(const f16x8*)&Ps[wv][ti * 16 + c16][c * 32 + g * 8];
        int tcol = c * 32 + g * 8;
#pragma unroll
        for (int td = 0; td < 2; ++td) {
            f16x8 vv = z8;
            if (tcol < VTS)
                vv = *(const f16x8*)(vt + vbase + (size_t)(td * 16 + c16) * VTS + tcol);
            vf[td] = vv;
        }
#pragma unroll
        for (int ti = 0; ti < 4; ++ti)
#pragma unroll
            for (int td = 0; td < 2; ++td)
                O[ti][td] = __builtin_amdgcn_mfma_f32_16x16x32_f16(pf[ti], vf[td], O[ti][td], 0, 0, 0);
    }

#pragma unroll
    for (int ti = 0; ti < 4; ++ti)
#pragma unroll
        for (int r = 0; r < 4; ++r) {
            int row = ti * 16 + g * 4 + r;
            if (row < NTOK) {
                size_t ob = ((size_t)(b * NTOK + row)) * DIM + h * HD;
                aout[ob + c16]      = (f16)O[ti][0][r];
                aout[ob + 16 + c16] = (f16)O[ti][1][r];
            }
        }
}

// ---------------- launcher ----------------
extern "C" void kernel_launch(void* const* d_in, const int* in_sizes, int n_in,
                              void* d_out, int out_size, void* d_ws, size_t ws_size,
                              hipStream_t stream) {
    const float* x      = (const float*)d_in[0];
    const float* mask   = (const float*)d_in[1];
    const float* rpb    = (const float*)d_in[2];
    const float* qkv_w  = (const float*)d_in[3];
    const float* qkv_b  = (const float*)d_in[4];
    const float* proj_w = (const float*)d_in[5];
    const float* proj_b = (const float*)d_in[6];
    float* out = (float*)d_out;

    char* ws = (char*)d_ws;
    size_t o = 0;
    f16* x16   = (f16*)(ws + o); o += (size_t)MTOT * DIM * 2;
    f16* w16   = (f16*)(ws + o); o += (size_t)1536 * 512 * 2;
    f16* pw16  = (f16*)(ws + o); o += (size_t)512 * 512 * 2;
    f16* qws   = (f16*)(ws + o); o += (size_t)NB * NH * NTOK * HD * 2;
    f16* kws   = (f16*)(ws + o); o += (size_t)NB * NH * NTOK * HD * 2;
    f16* vtws  = (f16*)(ws + o); o += (size_t)NB * NH * HD * VTS * 2;
    float* cb2 = (float*)(ws + o);
    f16* aout = x16;   // x16 dead after QKV GEMM

    cvt_f32_f16<<<dim3(2048), dim3(256), 0, stream>>>(x, x16, MTOT * DIM / 4);
    cvt_f32_f16<<<dim3(768), dim3(256), 0, stream>>>(qkv_w, w16, 1536 * 512 / 4);
    cvt_f32_f16<<<dim3(256), dim3(256), 0, stream>>>(proj_w, pw16, 512 * 512 / 4);

    build_comb2<<<dim3(16384), dim3(256), 0, stream>>>(rpb, mask, cb2);

    // QKV: 392 m-tiles x 6 n-tiles = 2352 blocks (divisible by 8)
    gemm256<0, 6><<<dim3((MTOT / 256) * 6), dim3(512), 0, stream>>>(
        x16, w16, qkv_b, qws, kws, vtws, nullptr);

    attn_kernel<<<dim3(NB * NH / 4), dim3(256), 0, stream>>>(qws, kws, vtws, cb2, aout);

    // proj: 392 x 2 = 784 blocks (divisible by 8)
    gemm256<1, 2><<<dim3((MTOT / 256) * 2), dim3(512), 0, stream>>>(
        aout, pw16, proj_b, nullptr, nullptr, nullptr, out);
}

// Round 6
// 604.483 us; speedup vs baseline: 1.1458x; 1.1458x over previous
//
#include <hip/hip_runtime.h>

typedef _Float16 f16;
typedef _Float16 f16x8 __attribute__((ext_vector_type(8)));
typedef _Float16 f16x4 __attribute__((ext_vector_type(4)));
typedef float f32x4 __attribute__((ext_vector_type(4)));

#define NTOK 49
#define NH 16
#define HD 32
#define DIM 512
#define NWIN 64
#define NB 2048
#define MTOT (NB*NTOK)      // 100352
#define SCALE 0.17677669529663687f
#define VTS 56              // vt t-stride (padded, 16B-aligned rows)

__device__ __forceinline__ void gload_lds16(const f16* g, f16* l) {
    __builtin_amdgcn_global_load_lds((const __attribute__((address_space(1))) void*)g,
                                     (__attribute__((address_space(3))) void*)l, 16, 0, 0);
}

// ---------------- convert fp32 -> fp16 (vectorized) ----------------
__global__ __launch_bounds__(256) void cvt_f32_f16(const float* __restrict__ s,
                                                   f16* __restrict__ d, int n4) {
    int i = blockIdx.x * 256 + threadIdx.x;
    int st = gridDim.x * 256;
    for (; i < n4; i += st) {
        float4 v = ((const float4*)s)[i];
        f16x4 o = { (f16)v.x, (f16)v.y, (f16)v.z, (f16)v.w };
        *(f16x4*)(d + (size_t)i * 4) = o;
    }
}

// ------- bias+mask in MFMA-fragment layout: comb2[w][h][lane][ti*4+tj][r] f32 -------
__global__ __launch_bounds__(256) void build_comb2(const float* __restrict__ rpb,
                                                   const float* __restrict__ mask,
                                                   float* __restrict__ comb2) {
    int idx = blockIdx.x * 256 + threadIdx.x;   // total = 1024 * 64 * 64
    int r4   = idx & 3;
    int tj   = (idx >> 2) & 3;
    int ti   = (idx >> 4) & 3;
    int lane = (idx >> 6) & 63;
    int wh   = idx >> 12;           // w*16 + h
    int h = wh & 15, w = wh >> 4;
    int g = lane >> 4, c16 = lane & 15;
    int row = ti * 16 + g * 4 + r4;
    int col = tj * 16 + c16;
    float v = 0.f;
    if (row < NTOK && col < NTOK) {
        int ri = row / 7, ci = row - ri * 7;
        int rj = col / 7, cj = col - rj * 7;
        int rel = (ri - rj + 6) * 13 + (ci - cj + 6);
        v = rpb[rel * NH + h] + mask[(w * NTOK + row) * NTOK + col];
    }
    comb2[idx] = v;
}

// ---------------- GEMM: C[m][n] = sum_k A[m][k]*B[n][k] + bias[n] ----------------
// 128x128 tile, BK=32, TRIPLE-buffered LDS (48KB -> 3 blocks/CU), one barrier per
// K-step, stage 2 steps ahead with counted vmcnt(4) (never drains in-flight pair).
// C^T accumulation: acc[j][i] = mfma(bf[j], af[i]) -> in-lane r spans 4 consecutive n
// (packed f16x4 / float4 epilogue stores). Source-side XOR swizzle chunk^=(row>>1)&3
// (2-way free on read, linear on gload write). T1 XCD-chunked grid. T5 setprio.
// MODE 0: q(*scale), k as [bid][t][d] f16x4-packed; v transposed scatter [bid][d][VTS]
// MODE 1: fp32 out[m*512+n] float4-packed
template<int MODE, int NT>   // NT = N/128 tiles
__global__ __launch_bounds__(256, 3) void gemm_kernel(const f16* __restrict__ A,
                                                      const f16* __restrict__ Bw,
                                                      const float* __restrict__ bias,
                                                      f16* __restrict__ qo,
                                                      f16* __restrict__ ko,
                                                      f16* __restrict__ vto,
                                                      float* __restrict__ outp) {
    __shared__ __align__(16) f16 As[3][128][32];
    __shared__ __align__(16) f16 Bs[3][128][32];

    const int tid = threadIdx.x;
    const int lane = tid & 63;
    const int wv = tid >> 6;
    const int wr = wv >> 1, wc = wv & 1;
    const int g = lane >> 4, c16 = lane & 15;
    const int rsw = (c16 >> 1) & 3;          // read-side swizzle (= (row>>1)&3, row_local = c16)

    // T1: bijective XCD-chunked remap (grid divisible by 8)
    const int nblk = gridDim.x;
    const int f = blockIdx.x;
    const int work = (f & 7) * (nblk >> 3) + (f >> 3);
    const int m0 = (work / NT) * 128;
    const int n0 = (work % NT) * 128;

    // staging: wave wv owns rows [wv*32, wv*32+32), 2 issues of 16 rows per matrix.
    // per-lane pre-swizzled source chunk; LDS dest linear (rule 21).
    const int srow = lane >> 2;                       // row within 16-row issue
    const int schunk = (lane & 3) ^ ((srow >> 1) & 3);
    const f16* gA = A  + (size_t)(m0 + wv * 32 + srow) * DIM + schunk * 8;
    const f16* gB = Bw + (size_t)(n0 + wv * 32 + srow) * DIM + schunk * 8;

#define STAGE(buf, t) do { \
    gload_lds16(gA + (t) * 32,                     &As[buf][wv * 32][0]);      \
    gload_lds16(gA + (size_t)16 * DIM + (t) * 32,  &As[buf][wv * 32 + 16][0]); \
    gload_lds16(gB + (t) * 32,                     &Bs[buf][wv * 32][0]);      \
    gload_lds16(gB + (size_t)16 * DIM + (t) * 32,  &Bs[buf][wv * 32 + 16][0]); \
} while (0)

    f32x4 acc[4][4];   // acc[j][i] = C^T: rows = n (tile j), cols = m (tile i)
#pragma unroll
    for (int j = 0; j < 4; ++j)
#pragma unroll
        for (int i = 0; i < 4; ++i)
            acc[j][i] = (f32x4){0.f, 0.f, 0.f, 0.f};

    // prologue: stage steps 0,1 into bufs 0,1
    STAGE(0, 0);
    STAGE(1, 1);
    asm volatile("s_waitcnt vmcnt(4)" ::: "memory");   // buf0 landed; buf1 in flight
    __builtin_amdgcn_s_barrier();

    const int KS = DIM / 32;   // 16 K-steps
#pragma unroll
    for (int t = 0; t < KS; ++t) {
        const int cb = t % 3;
        if (t + 2 < KS) STAGE((t + 2) % 3, t + 2);   // writes buf[(t-1)%3]: reads drained pre-barrier
        f16x8 af[4], bf[4];
#pragma unroll
        for (int i = 0; i < 4; ++i)
            af[i] = *(const f16x8*)&As[cb][wr * 64 + i * 16 + c16][(g ^ rsw) * 8];
#pragma unroll
        for (int j = 0; j < 4; ++j)
            bf[j] = *(const f16x8*)&Bs[cb][wc * 64 + j * 16 + c16][(g ^ rsw) * 8];
        __builtin_amdgcn_s_setprio(1);
#pragma unroll
        for (int j = 0; j < 4; ++j)
#pragma unroll
            for (int i = 0; i < 4; ++i)
                acc[j][i] = __builtin_amdgcn_mfma_f32_16x16x32_f16(bf[j], af[i], acc[j][i], 0, 0, 0);
        __builtin_amdgcn_s_setprio(0);
        asm volatile("s_waitcnt lgkmcnt(0)" ::: "memory");   // my ds_reads retired (buf reusable)
        __builtin_amdgcn_sched_barrier(0);
        if (t + 2 < KS) {
            asm volatile("s_waitcnt vmcnt(4)" ::: "memory"); // stage(t+1) landed, stage(t+2) flying
        } else if (t + 1 < KS) {
            asm volatile("s_waitcnt vmcnt(0)" ::: "memory"); // tail: last stage landed
        }
        if (t + 1 < KS) __builtin_amdgcn_s_barrier();
    }
#undef STAGE

    // ---- epilogue (C^T): per lane col m = i*16+c16 fixed; rows = 4 consecutive n ----
#pragma unroll
    for (int i = 0; i < 4; ++i) {
        const int m = m0 + wr * 64 + i * 16 + c16;
        int b = 0, tk = 0;
        if (MODE == 0) { b = m / NTOK; tk = m - b * NTOK; }
#pragma unroll
        for (int j = 0; j < 4; ++j) {
            const int n = n0 + wc * 64 + j * 16 + g * 4;
            f32x4 v = acc[j][i];
            const f32x4 b4 = *(const f32x4*)&bias[n];
            v += b4;
            if (MODE == 0) {
                const int s = n >> 9;
                const int hh = (n >> 5) & 15;
                const int d0 = n & 31;
                const size_t bh = (size_t)(b * NH + hh);
                if (s == 0) {
                    f16x4 o = { (f16)(v[0] * SCALE), (f16)(v[1] * SCALE),
                                (f16)(v[2] * SCALE), (f16)(v[3] * SCALE) };
                    *(f16x4*)(qo + (bh * NTOK + tk) * HD + d0) = o;
                } else if (s == 1) {
                    f16x4 o = { (f16)v[0], (f16)v[1], (f16)v[2], (f16)v[3] };
                    *(f16x4*)(ko + (bh * NTOK + tk) * HD + d0) = o;
                } else {
#pragma unroll
                    for (int r = 0; r < 4; ++r)
                        vto[(bh * HD + d0 + r) * VTS + tk] = (f16)v[r];
                }
            } else {
                float4 o = { v[0], v[1], v[2], v[3] };
                *(float4*)(outp + (size_t)m * DIM + n) = o;
            }
        }
    }
}

// ---------------- fused window attention: 4 waves/block, 1 wave per (b,h) ----------------
__global__ __launch_bounds__(256) void attn_kernel(const f16* __restrict__ qw,
                                                   const f16* __restrict__ kw,
                                                   const f16* __restrict__ vt,
                                                   const float* __restrict__ comb2,
                                                   f16* __restrict__ aout) {
    __shared__ __align__(16) f16 Ps[4][64][72];

    const int wv = threadIdx.x >> 6;
    const int l = threadIdx.x & 63;
    const int f = blockIdx.x;
    const int work = (f & 7) * (gridDim.x >> 3) + (f >> 3);
    const int bid = work * 4 + wv;
    const int b = bid >> 4, h = bid & 15;
    const int w = b & (NWIN - 1);
    const int g = l >> 4, c16 = l & 15;
    const size_t qkbase = (size_t)bid * (NTOK * HD);
    const size_t vbase = (size_t)bid * (HD * VTS);

    const f16x8 z8 = {};

    f16x8 qf[4], kf[4];
#pragma unroll
    for (int t = 0; t < 4; ++t) {
        int row = t * 16 + c16;
        f16x8 q = z8, k = z8;
        if (row < NTOK) {
            q = *(const f16x8*)(qw + qkbase + row * HD + g * 8);
            k = *(const f16x8*)(kw + qkbase + row * HD + g * 8);
        }
        qf[t] = q; kf[t] = k;
    }

    const float* cb = comb2 + (((size_t)(w * NH + h) * 64 + l) << 6);
    f32x4 S[4][4];
#pragma unroll
    for (int i = 0; i < 4; ++i)
#pragma unroll
        for (int j = 0; j < 4; ++j)
            S[i][j] = *(const f32x4*)(cb + (i * 4 + j) * 4);
#pragma unroll
    for (int i = 0; i < 4; ++i)
#pragma unroll
        for (int j = 0; j < 4; ++j)
            S[i][j] = __builtin_amdgcn_mfma_f32_16x16x32_f16(qf[i], kf[j], S[i][j], 0, 0, 0);

#pragma unroll
    for (int ti = 0; ti < 4; ++ti)
#pragma unroll
        for (int r = 0; r < 4; ++r) {
            int row = ti * 16 + g * 4 + r;
            float v0 = S[ti][0][r], v1 = S[ti][1][r], v2 = S[ti][2][r];
            float v3 = (c16 == 0) ? S[ti][3][r] : -1e30f;
            float mx = fmaxf(fmaxf(v0, v1), fmaxf(v2, v3));
#pragma unroll
            for (int mk = 1; mk < 16; mk <<= 1) mx = fmaxf(mx, __shfl_xor(mx, mk, 64));
            float p0 = __expf(v0 - mx), p1 = __expf(v1 - mx), p2 = __expf(v2 - mx);
            float p3 = (c16 == 0) ? __expf(v3 - mx) : 0.f;
            float sm = p0 + p1 + p2 + p3;
#pragma unroll
            for (int mk = 1; mk < 16; mk <<= 1) sm += __shfl_xor(sm, mk, 64);
            float inv = 1.f / sm;
            Ps[wv][row][c16]      = (f16)(p0 * inv);
            Ps[wv][row][16 + c16] = (f16)(p1 * inv);
            Ps[wv][row][32 + c16] = (f16)(p2 * inv);
            Ps[wv][row][48 + c16] = (f16)(p3 * inv);
        }
    __syncthreads();

    f32x4 O[4][2];
    const f32x4 zf = (f32x4){0.f, 0.f, 0.f, 0.f};
#pragma unroll
    for (int i = 0; i < 4; ++i) { O[i][0] = zf; O[i][1] = zf; }
#pragma unroll
    for (int c = 0; c < 2; ++c) {
        f16x8 pf[4], vf[2];
#pragma unroll
        for (int ti = 0; ti < 4; ++ti)
            pf[ti] = *(const f16x8*)&Ps[wv][ti * 16 + c16][c * 32 + g * 8];
        int tcol = c * 32 + g * 8;
#pragma unroll
        for (int td = 0; td < 2; ++td) {
            f16x8 vv = z8;
            if (tcol < VTS)
                vv = *(const f16x8*)(vt + vbase + (size_t)(td * 16 + c16) * VTS + tcol);
            vf[td] = vv;
        }
#pragma unroll
        for (int ti = 0; ti < 4; ++ti)
#pragma unroll
            for (int td = 0; td < 2; ++td)
                O[ti][td] = __builtin_amdgcn_mfma_f32_16x16x32_f16(pf[ti], vf[td], O[ti][td], 0, 0, 0);
    }

#pragma unroll
    for (int ti = 0; ti < 4; ++ti)
#pragma unroll
        for (int r = 0; r < 4; ++r) {
            int row = ti * 16 + g * 4 + r;
            if (row < NTOK) {
                size_t ob = ((size_t)(b * NTOK + row)) * DIM + h * HD;
                aout[ob + c16]      = (f16)O[ti][0][r];
                aout[ob + 16 + c16] = (f16)O[ti][1][r];
            }
        }
}

// ---------------- launcher ----------------
extern "C" void kernel_launch(void* const* d_in, const int* in_sizes, int n_in,
                              void* d_out, int out_size, void* d_ws, size_t ws_size,
                              hipStream_t stream) {
    const float* x      = (const float*)d_in[0];
    const float* mask   = (const float*)d_in[1];
    const float* rpb    = (const float*)d_in[2];
    const float* qkv_w  = (const float*)d_in[3];
    const float* qkv_b  = (const float*)d_in[4];
    const float* proj_w = (const float*)d_in[5];
    const float* proj_b = (const float*)d_in[6];
    float* out = (float*)d_out;

    char* ws = (char*)d_ws;
    size_t o = 0;
    f16* x16   = (f16*)(ws + o); o += (size_t)MTOT * DIM * 2;
    f16* w16   = (f16*)(ws + o); o += (size_t)1536 * 512 * 2;
    f16* pw16  = (f16*)(ws + o); o += (size_t)512 * 512 * 2;
    f16* qws   = (f16*)(ws + o); o += (size_t)NB * NH * NTOK * HD * 2;
    f16* kws   = (f16*)(ws + o); o += (size_t)NB * NH * NTOK * HD * 2;
    f16* vtws  = (f16*)(ws + o); o += (size_t)NB * NH * HD * VTS * 2;
    float* cb2 = (float*)(ws + o);
    f16* aout = x16;   // x16 dead after QKV GEMM

    cvt_f32_f16<<<dim3(2048), dim3(256), 0, stream>>>(x, x16, MTOT * DIM / 4);
    cvt_f32_f16<<<dim3(768), dim3(256), 0, stream>>>(qkv_w, w16, 1536 * 512 / 4);
    cvt_f32_f16<<<dim3(256), dim3(256), 0, stream>>>(proj_w, pw16, 512 * 512 / 4);

    build_comb2<<<dim3(16384), dim3(256), 0, stream>>>(rpb, mask, cb2);

    // QKV: 784 m-tiles x 12 n-tiles = 9408 blocks (divisible by 8)
    gemm_kernel<0, 12><<<dim3((MTOT / 128) * 12), dim3(256), 0, stream>>>(
        x16, w16, qkv_b, qws, kws, vtws, nullptr);

    attn_kernel<<<dim3(NB * NH / 4), dim3(256), 0, stream>>>(qws, kws, vtws, cb2, aout);

    // proj: 784 x 4 = 3136 blocks (divisible by 8)
    gemm_kernel<1, 4><<<dim3((MTOT / 128) * 4), dim3(256), 0, stream>>>(
        aout, pw16, proj_b, nullptr, nullptr, nullptr, out);
}

// Round 7
// 579.472 us; speedup vs baseline: 1.1953x; 1.0432x over previous
//
#include <hip/hip_runtime.h>

typedef _Float16 f16;
typedef _Float16 f16x8 __attribute__((ext_vector_type(8)));
typedef _Float16 f16x4 __attribute__((ext_vector_type(4)));
typedef float f32x4 __attribute__((ext_vector_type(4)));

#define NTOK 49
#define NH 16
#define HD 32
#define DIM 512
#define NWIN 64
#define NB 2048
#define MTOT (NB*NTOK)      // 100352
#define SCALE 0.17677669529663687f
#define VTS 56              // vt t-stride (padded, 16B-aligned rows)

__device__ __forceinline__ void gload_lds16(const f16* g, f16* l) {
    __builtin_amdgcn_global_load_lds((const __attribute__((address_space(1))) void*)g,
                                     (__attribute__((address_space(3))) void*)l, 16, 0, 0);
}

// ---------------- convert fp32 -> fp16 (vectorized) ----------------
__global__ __launch_bounds__(256) void cvt_f32_f16(const float* __restrict__ s,
                                                   f16* __restrict__ d, int n4) {
    int i = blockIdx.x * 256 + threadIdx.x;
    int st = gridDim.x * 256;
    for (; i < n4; i += st) {
        float4 v = ((const float4*)s)[i];
        f16x4 o = { (f16)v.x, (f16)v.y, (f16)v.z, (f16)v.w };
        *(f16x4*)(d + (size_t)i * 4) = o;
    }
}

// ------- bias+mask in MFMA-fragment layout, f16: comb2[w][h][lane][ti*4+tj][r] -------
__global__ __launch_bounds__(256) void build_comb2(const float* __restrict__ rpb,
                                                   const float* __restrict__ mask,
                                                   f16* __restrict__ comb2) {
    int idx = blockIdx.x * 256 + threadIdx.x;   // total = 1024 * 64 * 64
    int r4   = idx & 3;
    int tj   = (idx >> 2) & 3;
    int ti   = (idx >> 4) & 3;
    int lane = (idx >> 6) & 63;
    int wh   = idx >> 12;           // w*16 + h
    int h = wh & 15, w = wh >> 4;
    int g = lane >> 4, c16 = lane & 15;
    int row = ti * 16 + g * 4 + r4;
    int col = tj * 16 + c16;
    float v = 0.f;
    if (row < NTOK && col < NTOK) {
        int ri = row / 7, ci = row - ri * 7;
        int rj = col / 7, cj = col - rj * 7;
        int rel = (ri - rj + 6) * 13 + (ci - cj + 6);
        v = rpb[rel * NH + h] + mask[(w * NTOK + row) * NTOK + col];
    }
    comb2[idx] = (f16)v;
}

// ---------------- 256x256 GEMM: C[m][n] = sum_k A[m][k]*B[n][k] + bias[n] ----------------
// 8 waves (2Mx4N, 128x64 per wave), BK=32, QUAD-buffered 128KB LDS, stage 3 steps
// ahead, counted vmcnt(8) (waits only ~3-step-old loads), one barrier per step.
// C^T accumulation (acc[j][i] = mfma(bf,af)) -> packed f16x4/float4 epilogue stores.
// Source-side XOR swizzle chunk^=(row>>1)&3 (0-conflict verified r6). T1 grid. T5.
// MODE 0: q(*scale), k as [bid][t][d] f16x4-packed; v transposed scatter [bid][d][VTS]
// MODE 1: fp32 out[m*512+n] float4-packed
template<int MODE, int NT>   // NT = N/256 tiles
__global__ __launch_bounds__(512, 1) void gemm_kernel(const f16* __restrict__ A,
                                                      const f16* __restrict__ Bw,
                                                      const float* __restrict__ bias,
                                                      f16* __restrict__ qo,
                                                      f16* __restrict__ ko,
                                                      f16* __restrict__ vto,
                                                      float* __restrict__ outp) {
    __shared__ __align__(16) f16 As[4][256][32];
    __shared__ __align__(16) f16 Bs[4][256][32];

    const int tid = threadIdx.x;
    const int lane = tid & 63;
    const int wv = tid >> 6;                 // 0..7
    const int wm = wv >> 2, wn = wv & 3;     // 2 x 4 wave grid
    const int g = lane >> 4, c16 = lane & 15;
    const int rsw = (c16 >> 1) & 3;          // read-side swizzle

    // T1: bijective XCD-chunked remap (grid divisible by 8)
    const int nblk = gridDim.x;
    const int f = blockIdx.x;
    const int work = (f & 7) * (nblk >> 3) + (f >> 3);
    const int m0 = (work / NT) * 256;
    const int n0 = (work % NT) * 256;

    // staging: per wave 4 issues of 16 rows x 32 f16 (1KB each): A-lo/A-hi/B-lo/B-hi.
    // lane -> (row = lane>>2, chunk = lane&3); source chunk pre-swizzled (rule 21).
    const int srow = lane >> 2;
    const int schunk = (lane & 3) ^ ((srow >> 1) & 3);
    const f16* gAlo = A  + (size_t)(m0 + wv * 16 + srow) * DIM + schunk * 8;
    const f16* gAhi = gAlo + (size_t)128 * DIM;
    const f16* gBlo = Bw + (size_t)(n0 + wv * 16 + srow) * DIM + schunk * 8;
    const f16* gBhi = gBlo + (size_t)128 * DIM;

#define STAGE(t) do { const int _b = (t) & 3; const int _k = (t) * 32;     \
    gload_lds16(gAlo + _k, &As[_b][wv * 16][0]);                           \
    gload_lds16(gAhi + _k, &As[_b][128 + wv * 16][0]);                     \
    gload_lds16(gBlo + _k, &Bs[_b][wv * 16][0]);                           \
    gload_lds16(gBhi + _k, &Bs[_b][128 + wv * 16][0]); } while (0)

    f32x4 acc[4][8];   // acc[j][i] = C^T block: j over n (wn*64+j*16), i over m (wm*128+i*16)
#pragma unroll
    for (int j = 0; j < 4; ++j)
#pragma unroll
        for (int i = 0; i < 8; ++i)
            acc[j][i] = (f32x4){0.f, 0.f, 0.f, 0.f};

    // prologue: stage steps 0,1,2
    STAGE(0); STAGE(1); STAGE(2);
    asm volatile("s_waitcnt vmcnt(8)" ::: "memory");   // step-0 stage landed; 1,2 in flight
    __builtin_amdgcn_s_barrier();

    const int KS = DIM / 32;   // 16 K-steps
#pragma unroll
    for (int t = 0; t < KS; ++t) {
        const int cb = t & 3;
        if (t + 3 < KS) STAGE(t + 3);   // buf (t-1)&3: its readers drained before prev barrier
        f16x8 af[8], bf[4];
#pragma unroll
        for (int i = 0; i < 8; ++i)
            af[i] = *(const f16x8*)&As[cb][wm * 128 + i * 16 + c16][(g ^ rsw) * 8];
#pragma unroll
        for (int j = 0; j < 4; ++j)
            bf[j] = *(const f16x8*)&Bs[cb][wn * 64 + j * 16 + c16][(g ^ rsw) * 8];
        __builtin_amdgcn_s_setprio(1);
#pragma unroll
        for (int j = 0; j < 4; ++j)
#pragma unroll
            for (int i = 0; i < 8; ++i)
                acc[j][i] = __builtin_amdgcn_mfma_f32_16x16x32_f16(bf[j], af[i], acc[j][i], 0, 0, 0);
        __builtin_amdgcn_s_setprio(0);
        asm volatile("s_waitcnt lgkmcnt(0)" ::: "memory");   // my ds_reads retired
        __builtin_amdgcn_sched_barrier(0);
        if (t + 3 < KS) {
            asm volatile("s_waitcnt vmcnt(8)" ::: "memory"); // stage(t+1) landed; t+2,t+3 flying
        } else if (t + 2 < KS) {
            asm volatile("s_waitcnt vmcnt(4)" ::: "memory"); // stage(t+1) landed; t+2 flying
        } else if (t + 1 < KS) {
            asm volatile("s_waitcnt vmcnt(0)" ::: "memory"); // last stage landed
        }
        if (t + 1 < KS) __builtin_amdgcn_s_barrier();
    }
#undef STAGE

    // ---- epilogue (C^T): per lane col m = wm*128+i*16+c16; rows = 4 consecutive n ----
#pragma unroll
    for (int i = 0; i < 8; ++i) {
        const int m = m0 + wm * 128 + i * 16 + c16;
        int b = 0, tk = 0;
        if (MODE == 0) { b = m / NTOK; tk = m - b * NTOK; }
#pragma unroll
        for (int j = 0; j < 4; ++j) {
            const int n = n0 + wn * 64 + j * 16 + g * 4;
            f32x4 v = acc[j][i];
            const f32x4 b4 = *(const f32x4*)&bias[n];
            v += b4;
            if (MODE == 0) {
                const int s = n >> 9;
                const int hh = (n >> 5) & 15;
                const int d0 = n & 31;
                const size_t bh = (size_t)(b * NH + hh);
                if (s == 0) {
                    f16x4 o = { (f16)(v[0] * SCALE), (f16)(v[1] * SCALE),
                                (f16)(v[2] * SCALE), (f16)(v[3] * SCALE) };
                    *(f16x4*)(qo + (bh * NTOK + tk) * HD + d0) = o;
                } else if (s == 1) {
                    f16x4 o = { (f16)v[0], (f16)v[1], (f16)v[2], (f16)v[3] };
                    *(f16x4*)(ko + (bh * NTOK + tk) * HD + d0) = o;
                } else {
#pragma unroll
                    for (int r = 0; r < 4; ++r)
                        vto[(bh * HD + d0 + r) * VTS + tk] = (f16)v[r];
                }
            } else {
                float4 o = { v[0], v[1], v[2], v[3] };
                *(float4*)(outp + (size_t)m * DIM + n) = o;
            }
        }
    }
}

// ---------------- fused window attention: 4 waves/block, 1 wave per (b,h) ----------------
__global__ __launch_bounds__(256) void attn_kernel(const f16* __restrict__ qw,
                                                   const f16* __restrict__ kw,
                                                   const f16* __restrict__ vt,
                                                   const f16* __restrict__ comb2,
                                                   f16* __restrict__ aout) {
    __shared__ __align__(16) f16 Ps[4][64][72];

    const int wv = threadIdx.x >> 6;
    const int l = threadIdx.x & 63;
    const int f = blockIdx.x;
    const int work = (f & 7) * (gridDim.x >> 3) + (f >> 3);
    const int bid = work * 4 + wv;
    const int b = bid >> 4, h = bid & 15;
    const int w = b & (NWIN - 1);
    const int g = l >> 4, c16 = l & 15;
    const size_t qkbase = (size_t)bid * (NTOK * HD);
    const size_t vbase = (size_t)bid * (HD * VTS);

    const f16x8 z8 = {};

    f16x8 qf[4], kf[4];
#pragma unroll
    for (int t = 0; t < 4; ++t) {
        int row = t * 16 + c16;
        f16x8 q = z8, k = z8;
        if (row < NTOK) {
            q = *(const f16x8*)(qw + qkbase + row * HD + g * 8);
            k = *(const f16x8*)(kw + qkbase + row * HD + g * 8);
        }
        qf[t] = q; kf[t] = k;
    }

    // f16 bias+mask table in fragment layout -> convert to f32 C-init
    const f16* cb = comb2 + (((size_t)(w * NH + h) * 64 + l) << 6);
    f16x8 cbv[8];
#pragma unroll
    for (int k = 0; k < 8; ++k) cbv[k] = *(const f16x8*)(cb + k * 8);
    f32x4 S[4][4];
#pragma unroll
    for (int i = 0; i < 4; ++i)
#pragma unroll
        for (int j = 0; j < 4; ++j) {
            const int e = i * 16 + j * 4;
#pragma unroll
            for (int r = 0; r < 4; ++r)
                S[i][j][r] = (float)cbv[(e + r) >> 3][(e + r) & 7];
        }
#pragma unroll
    for (int i = 0; i < 4; ++i)
#pragma unroll
        for (int j = 0; j < 4; ++j)
            S[i][j] = __builtin_amdgcn_mfma_f32_16x16x32_f16(qf[i], kf[j], S[i][j], 0, 0, 0);

#pragma unroll
    for (int ti = 0; ti < 4; ++ti)
#pragma unroll
        for (int r = 0; r < 4; ++r) {
            int row = ti * 16 + g * 4 + r;
            float v0 = S[ti][0][r], v1 = S[ti][1][r], v2 = S[ti][2][r];
            float v3 = (c16 == 0) ? S[ti][3][r] : -1e30f;
            float mx = fmaxf(fmaxf(v0, v1), fmaxf(v2, v3));
#pragma unroll
            for (int mk = 1; mk < 16; mk <<= 1) mx = fmaxf(mx, __shfl_xor(mx, mk, 64));
            float p0 = __expf(v0 - mx), p1 = __expf(v1 - mx), p2 = __expf(v2 - mx);
            float p3 = (c16 == 0) ? __expf(v3 - mx) : 0.f;
            float sm = p0 + p1 + p2 + p3;
#pragma unroll
            for (int mk = 1; mk < 16; mk <<= 1) sm += __shfl_xor(sm, mk, 64);
            float inv = 1.f / sm;
            Ps[wv][row][c16]      = (f16)(p0 * inv);
            Ps[wv][row][16 + c16] = (f16)(p1 * inv);
            Ps[wv][row][32 + c16] = (f16)(p2 * inv);
            Ps[wv][row][48 + c16] = (f16)(p3 * inv);
        }
    __syncthreads();

    // O^T = V^T P^T via mfma(vf, pf): lane col = q-token (c16), rows = 4 consecutive d
    f32x4 O2[2][4];
    const f32x4 zf = (f32x4){0.f, 0.f, 0.f, 0.f};
#pragma unroll
    for (int td = 0; td < 2; ++td)
#pragma unroll
        for (int ti = 0; ti < 4; ++ti) O2[td][ti] = zf;
#pragma unroll
    for (int c = 0; c < 2; ++c) {
        f16x8 pf[4], vf[2];
#pragma unroll
        for (int ti = 0; ti < 4; ++ti)
            pf[ti] = *(const f16x8*)&Ps[wv][ti * 16 + c16][c * 32 + g * 8];
        int tcol = c * 32 + g * 8;
#pragma unroll
        for (int td = 0; td < 2; ++td) {
            f16x8 vv = z8;
            if (tcol < VTS)
                vv = *(const f16x8*)(vt + vbase + (size_t)(td * 16 + c16) * VTS + tcol);
            vf[td] = vv;
        }
#pragma unroll
        for (int td = 0; td < 2; ++td)
#pragma unroll
            for (int ti = 0; ti < 4; ++ti)
                O2[td][ti] = __builtin_amdgcn_mfma_f32_16x16x32_f16(vf[td], pf[ti], O2[td][ti], 0, 0, 0);
    }

    // packed f16x4 stores: tok = ti*16+c16, d0 = td*16+g*4
#pragma unroll
    for (int ti = 0; ti < 4; ++ti) {
        int tok = ti * 16 + c16;
        if (tok < NTOK) {
            size_t ob = ((size_t)(b * NTOK + tok)) * DIM + h * HD;
#pragma unroll
            for (int td = 0; td < 2; ++td) {
                f32x4 v = O2[td][ti];
                f16x4 o = { (f16)v[0], (f16)v[1], (f16)v[2], (f16)v[3] };
                *(f16x4*)(aout + ob + td * 16 + g * 4) = o;
            }
        }
    }
}

// ---------------- launcher ----------------
extern "C" void kernel_launch(void* const* d_in, const int* in_sizes, int n_in,
                              void* d_out, int out_size, void* d_ws, size_t ws_size,
                              hipStream_t stream) {
    const float* x      = (const float*)d_in[0];
    const float* mask   = (const float*)d_in[1];
    const float* rpb    = (const float*)d_in[2];
    const float* qkv_w  = (const float*)d_in[3];
    const float* qkv_b  = (const float*)d_in[4];
    const float* proj_w = (const float*)d_in[5];
    const float* proj_b = (const float*)d_in[6];
    float* out = (float*)d_out;

    char* ws = (char*)d_ws;
    size_t o = 0;
    f16* x16   = (f16*)(ws + o); o += (size_t)MTOT * DIM * 2;
    f16* w16   = (f16*)(ws + o); o += (size_t)1536 * 512 * 2;
    f16* pw16  = (f16*)(ws + o); o += (size_t)512 * 512 * 2;
    f16* qws   = (f16*)(ws + o); o += (size_t)NB * NH * NTOK * HD * 2;
    f16* kws   = (f16*)(ws + o); o += (size_t)NB * NH * NTOK * HD * 2;
    f16* vtws  = (f16*)(ws + o); o += (size_t)NB * NH * HD * VTS * 2;
    f16* cb2   = (f16*)(ws + o);
    f16* aout = x16;   // x16 dead after QKV GEMM

    cvt_f32_f16<<<dim3(2048), dim3(256), 0, stream>>>(x, x16, MTOT * DIM / 4);
    cvt_f32_f16<<<dim3(768), dim3(256), 0, stream>>>(qkv_w, w16, 1536 * 512 / 4);
    cvt_f32_f16<<<dim3(256), dim3(256), 0, stream>>>(proj_w, pw16, 512 * 512 / 4);

    build_comb2<<<dim3(16384), dim3(256), 0, stream>>>(rpb, mask, cb2);

    // QKV: 392 m-tiles x 6 n-tiles = 2352 blocks (divisible by 8)
    gemm_kernel<0, 6><<<dim3((MTOT / 256) * 6), dim3(512), 0, stream>>>(
        x16, w16, qkv_b, qws, kws, vtws, nullptr);

    attn_kernel<<<dim3(NB * NH / 4), dim3(256), 0, stream>>>(qws, kws, vtws, cb2, aout);

    // proj: 392 x 2 = 784 blocks (divisible by 8)
    gemm_kernel<1, 2><<<dim3((MTOT / 256) * 2), dim3(512), 0, stream>>>(
        aout, pw16, proj_b, nullptr, nullptr, nullptr, out);
}

// Round 8
// 567.906 us; speedup vs baseline: 1.2196x; 1.0204x over previous
//
#include <hip/hip_runtime.h>

typedef _Float16 f16;
typedef _Float16 f16x8 __attribute__((ext_vector_type(8)));
typedef _Float16 f16x4 __attribute__((ext_vector_type(4)));
typedef float f32x4 __attribute__((ext_vector_type(4)));

#define NTOK 49
#define NH 16
#define HD 32
#define DIM 512
#define NWIN 64
#define NB 2048
#define MTOT (NB*NTOK)      // 100352
#define SCALE 0.17677669529663687f
#define VTS 56              // vt t-stride (padded, 16B-aligned rows)

__device__ __forceinline__ void gload_lds16(const f16* g, f16* l) {
    __builtin_amdgcn_global_load_lds((const __attribute__((address_space(1))) void*)g,
                                     (__attribute__((address_space(3))) void*)l, 16, 0, 0);
}

// ---------------- convert fp32 -> fp16 (vectorized) ----------------
__global__ __launch_bounds__(256) void cvt_f32_f16(const float* __restrict__ s,
                                                   f16* __restrict__ d, int n4) {
    int i = blockIdx.x * 256 + threadIdx.x;
    int st = gridDim.x * 256;
    for (; i < n4; i += st) {
        float4 v = ((const float4*)s)[i];
        f16x4 o = { (f16)v.x, (f16)v.y, (f16)v.z, (f16)v.w };
        *(f16x4*)(d + (size_t)i * 4) = o;
    }
}

// ------- bias+mask in MFMA-fragment layout, f16: comb2[w][h][lane][ti*4+tj][r] -------
__global__ __launch_bounds__(256) void build_comb2(const float* __restrict__ rpb,
                                                   const float* __restrict__ mask,
                                                   f16* __restrict__ comb2) {
    int idx = blockIdx.x * 256 + threadIdx.x;   // total = 1024 * 64 * 64
    int r4   = idx & 3;
    int tj   = (idx >> 2) & 3;
    int ti   = (idx >> 4) & 3;
    int lane = (idx >> 6) & 63;
    int wh   = idx >> 12;           // w*16 + h
    int h = wh & 15, w = wh >> 4;
    int g = lane >> 4, c16 = lane & 15;
    int row = ti * 16 + g * 4 + r4;
    int col = tj * 16 + c16;
    float v = 0.f;
    if (row < NTOK && col < NTOK) {
        int ri = row / 7, ci = row - ri * 7;
        int rj = col / 7, cj = col - rj * 7;
        int rel = (ri - rj + 6) * 13 + (ci - cj + 6);
        v = rpb[rel * NH + h] + mask[(w * NTOK + row) * NTOK + col];
    }
    comb2[idx] = (f16)v;
}

#define WAIT_LGKM do { asm volatile("s_waitcnt lgkmcnt(0)" ::: "memory"); \
                       __builtin_amdgcn_sched_barrier(0); } while (0)
#define WAIT_VM(N) do { asm volatile("s_waitcnt vmcnt(" #N ")" ::: "memory"); \
                        __builtin_amdgcn_sched_barrier(0); } while (0)

// ---------------- 256x256 8-phase GEMM (m201-style, BK=64) ----------------
// C[m][n] = sum_k A[m][k]*B[n][k] + bias[n]
// 8 waves (2Mx4N, 128x64/wave), BK=64, 2-buffer 128KB LDS. Per K-tile 4 quadrant
// phases {ds_reads; stage 1 half-tile; barrier; lgkm0; setprio+16 MFMA; barrier}
// with register retention (reads 12/8/4/0). Staggered staging: t+1's A-hi/B-hi at
// p0/p1 (other buf), t+2's A-lo/B-lo at p2/p3 (current buf; regions dead after
// p1/p2 lgkm). Gate vmcnt(4) at end of p3 retires exactly tile t+1, keeps 2
// half-tiles in flight. C^T accumulation -> packed f16x4/float4 stores.
// Swizzle: chunk ^= row&7 on source + read (0-conflict family, r2-r4 verified).
// MODE 0: q(*scale), k as [bid][t][d]; v transposed scatter [bid][d][VTS]
// MODE 1: fp32 out[m*512+n]
template<int MODE, int NT>   // NT = N/256 tiles
__global__ __launch_bounds__(512, 2) void gemm_kernel(const f16* __restrict__ A,
                                                      const f16* __restrict__ Bw,
                                                      const float* __restrict__ bias,
                                                      f16* __restrict__ qo,
                                                      f16* __restrict__ ko,
                                                      f16* __restrict__ vto,
                                                      float* __restrict__ outp) {
    __shared__ __align__(16) f16 As[2][256][64];
    __shared__ __align__(16) f16 Bs[2][256][64];

    const int tid = threadIdx.x;
    const int lane = tid & 63;
    const int wv = tid >> 6;                 // 0..7
    const int wm = wv >> 2, wn = wv & 3;     // 2M x 4N wave grid
    const int g = lane >> 4, c16 = lane & 15;

    // T1: bijective XCD-chunked remap (grid divisible by 8)
    const int nblk = gridDim.x;
    const int f = blockIdx.x;
    const int work = (f & 7) * (nblk >> 3) + (f >> 3);
    const int m0 = (work / NT) * 256;
    const int n0 = (work % NT) * 256;

    // staging: half-tile = 128 rows x 64 f16 (16KB) of one matrix-half; 2 gloads/thread.
    // lane -> row = lane>>3 (within 8-row group), chunk = lane&7, pre-swizzled source.
    const int srow = lane >> 3;
    const int schunk = (lane & 7) ^ srow;
    const f16* gA = A  + (size_t)(m0 + wv * 16 + srow) * DIM + schunk * 8;
    const f16* gB = Bw + (size_t)(n0 + wv * 16 + srow) * DIM + schunk * 8;

    // role: 0=A-lo 1=A-hi 2=B-lo 3=B-hi
#define STAGE(buf, kt, role) do {                                              \
    const f16* _s = (((role) < 2) ? gA : gB) + (size_t)(((role) & 1) * 128) * DIM + (kt) * 64; \
    f16* _d = ((role) < 2) ? &As[buf][((role) & 1) * 128 + wv * 16][0]         \
                           : &Bs[buf][((role) & 1) * 128 + wv * 16][0];        \
    gload_lds16(_s, _d);                                                       \
    gload_lds16(_s + (size_t)8 * DIM, _d + 8 * 64);                            \
} while (0)

#define ARD(b, qr, t2, kk) (*(const f16x8*)&As[b][wm * 128 + (qr) * 64 + (t2) * 16 + c16][(((kk) * 4 + g) ^ (c16 & 7)) * 8])
#define BRD(b, qc, j2, kk) (*(const f16x8*)&Bs[b][wn * 64 + (qc) * 32 + (j2) * 16 + c16][(((kk) * 4 + g) ^ (c16 & 7)) * 8])

#define MM(qc, qr, BF, AF) do {                                                \
    _Pragma("unroll") for (int _j = 0; _j < 2; ++_j)                           \
    _Pragma("unroll") for (int _i = 0; _i < 4; ++_i)                           \
    _Pragma("unroll") for (int _k = 0; _k < 2; ++_k)                           \
        acc[(qc) * 2 + _j][(qr) * 4 + _i] = __builtin_amdgcn_mfma_f32_16x16x32_f16( \
            (BF)[_j][_k], (AF)[_i][_k], acc[(qc) * 2 + _j][(qr) * 4 + _i], 0, 0, 0); \
} while (0)

    f32x4 acc[4][8];   // acc[j][i] = C^T: j over n-tiles (wn*64+j*16), i over m-tiles (wm*128+i*16)
#pragma unroll
    for (int j = 0; j < 4; ++j)
#pragma unroll
        for (int i = 0; i < 8; ++i)
            acc[j][i] = (f32x4){0.f, 0.f, 0.f, 0.f};

    const int KT = DIM / 64;   // 8 K-tiles

    // prologue: tile 0 complete + tile 1 A-lo,B-lo; gate leaves those 2 in flight
    STAGE(0, 0, 0); STAGE(0, 0, 2); STAGE(0, 0, 1); STAGE(0, 0, 3);
    STAGE(1, 1, 0); STAGE(1, 1, 2);
    WAIT_VM(4);
    __builtin_amdgcn_s_barrier();

#pragma unroll
    for (int t = 0; t < KT; ++t) {
        const int b = t & 1, nb = b ^ 1;
        f16x8 af0[4][2], af1[4][2], bf0[2][2], bf1[2][2];

        // ---- p0: Q(0,0) — read af0 (8) + bf0 (4); stage t+1 A-hi ----
#pragma unroll
        for (int t2 = 0; t2 < 4; ++t2)
#pragma unroll
            for (int kk = 0; kk < 2; ++kk) af0[t2][kk] = ARD(b, 0, t2, kk);
#pragma unroll
        for (int j2 = 0; j2 < 2; ++j2)
#pragma unroll
            for (int kk = 0; kk < 2; ++kk) bf0[j2][kk] = BRD(b, 0, j2, kk);
        if (t + 1 < KT) STAGE(nb, t + 1, 1);
        __builtin_amdgcn_s_barrier();
        WAIT_LGKM;
        __builtin_amdgcn_s_setprio(1);
        MM(0, 0, bf0, af0);
        __builtin_amdgcn_s_setprio(0);
        __builtin_amdgcn_s_barrier();

        // ---- p1: Q(1,0) — read af1 (8); bf0 retained; stage t+1 B-hi ----
#pragma unroll
        for (int t2 = 0; t2 < 4; ++t2)
#pragma unroll
            for (int kk = 0; kk < 2; ++kk) af1[t2][kk] = ARD(b, 1, t2, kk);
        if (t + 1 < KT) STAGE(nb, t + 1, 3);
        __builtin_amdgcn_s_barrier();
        WAIT_LGKM;
        __builtin_amdgcn_s_setprio(1);
        MM(0, 1, bf0, af1);
        __builtin_amdgcn_s_setprio(0);
        __builtin_amdgcn_s_barrier();

        // ---- p2: Q(0,1) — read bf1 (4); af0 retained; stage t+2 A-lo (curr buf, A dead after p1) ----
#pragma unroll
        for (int j2 = 0; j2 < 2; ++j2)
#pragma unroll
            for (int kk = 0; kk < 2; ++kk) bf1[j2][kk] = BRD(b, 1, j2, kk);
        if (t + 2 < KT) STAGE(b, t + 2, 0);
        __builtin_amdgcn_s_barrier();
        WAIT_LGKM;
        __builtin_amdgcn_s_setprio(1);
        MM(1, 0, bf1, af0);
        __builtin_amdgcn_s_setprio(0);
        __builtin_amdgcn_s_barrier();

        // ---- p3: Q(1,1) — all retained; stage t+2 B-lo; gate before closing barrier ----
        if (t + 2 < KT) STAGE(b, t + 2, 2);
        __builtin_amdgcn_s_setprio(1);
        MM(1, 1, bf1, af1);
        __builtin_amdgcn_s_setprio(0);
        if (t == KT - 2) { WAIT_VM(0); }
        else if (t < KT - 2) { WAIT_VM(4); }
        __builtin_amdgcn_s_barrier();
    }
#undef STAGE
#undef ARD
#undef BRD
#undef MM

    // ---- epilogue (C^T): per lane col m = wm*128+i*16+c16; rows = 4 consecutive n ----
#pragma unroll
    for (int i = 0; i < 8; ++i) {
        const int m = m0 + wm * 128 + i * 16 + c16;
        int bb = 0, tk = 0;
        if (MODE == 0) { bb = m / NTOK; tk = m - bb * NTOK; }
#pragma unroll
        for (int j = 0; j < 4; ++j) {
            const int n = n0 + wn * 64 + j * 16 + g * 4;
            f32x4 v = acc[j][i];
            const f32x4 b4 = *(const f32x4*)&bias[n];
            v += b4;
            if (MODE == 0) {
                const int s = n >> 9;
                const int hh = (n >> 5) & 15;
                const int d0 = n & 31;
                const size_t bh = (size_t)(bb * NH + hh);
                if (s == 0) {
                    f16x4 o = { (f16)(v[0] * SCALE), (f16)(v[1] * SCALE),
                                (f16)(v[2] * SCALE), (f16)(v[3] * SCALE) };
                    *(f16x4*)(qo + (bh * NTOK + tk) * HD + d0) = o;
                } else if (s == 1) {
                    f16x4 o = { (f16)v[0], (f16)v[1], (f16)v[2], (f16)v[3] };
                    *(f16x4*)(ko + (bh * NTOK + tk) * HD + d0) = o;
                } else {
#pragma unroll
                    for (int r = 0; r < 4; ++r)
                        vto[(bh * HD + d0 + r) * VTS + tk] = (f16)v[r];
                }
            } else {
                float4 o = { v[0], v[1], v[2], v[3] };
                *(float4*)(outp + (size_t)m * DIM + n) = o;
            }
        }
    }
}

// ---------------- fused window attention: 4 waves/block, 1 wave per (b,h) ----------------
__global__ __launch_bounds__(256) void attn_kernel(const f16* __restrict__ qw,
                                                   const f16* __restrict__ kw,
                                                   const f16* __restrict__ vt,
                                                   const f16* __restrict__ comb2,
                                                   f16* __restrict__ aout) {
    __shared__ __align__(16) f16 Ps[4][64][72];

    const int wv = threadIdx.x >> 6;
    const int l = threadIdx.x & 63;
    const int f = blockIdx.x;
    const int work = (f & 7) * (gridDim.x >> 3) + (f >> 3);
    const int bid = work * 4 + wv;
    const int b = bid >> 4, h = bid & 15;
    const int w = b & (NWIN - 1);
    const int g = l >> 4, c16 = l & 15;
    const size_t qkbase = (size_t)bid * (NTOK * HD);
    const size_t vbase = (size_t)bid * (HD * VTS);

    const f16x8 z8 = {};

    f16x8 qf[4], kf[4];
#pragma unroll
    for (int t = 0; t < 4; ++t) {
        int row = t * 16 + c16;
        f16x8 q = z8, k = z8;
        if (row < NTOK) {
            q = *(const f16x8*)(qw + qkbase + row * HD + g * 8);
            k = *(const f16x8*)(kw + qkbase + row * HD + g * 8);
        }
        qf[t] = q; kf[t] = k;
    }

    // f16 bias+mask table in fragment layout -> f32 C-init
    const f16* cb = comb2 + (((size_t)(w * NH + h) * 64 + l) << 6);
    f16x8 cbv[8];
#pragma unroll
    for (int k = 0; k < 8; ++k) cbv[k] = *(const f16x8*)(cb + k * 8);
    f32x4 S[4][4];
#pragma unroll
    for (int i = 0; i < 4; ++i)
#pragma unroll
        for (int j = 0; j < 4; ++j) {
            const int e = i * 16 + j * 4;
#pragma unroll
            for (int r = 0; r < 4; ++r)
                S[i][j][r] = (float)cbv[(e + r) >> 3][(e + r) & 7];
        }
#pragma unroll
    for (int i = 0; i < 4; ++i)
#pragma unroll
        for (int j = 0; j < 4; ++j)
            S[i][j] = __builtin_amdgcn_mfma_f32_16x16x32_f16(qf[i], kf[j], S[i][j], 0, 0, 0);

#pragma unroll
    for (int ti = 0; ti < 4; ++ti)
#pragma unroll
        for (int r = 0; r < 4; ++r) {
            int row = ti * 16 + g * 4 + r;
            float v0 = S[ti][0][r], v1 = S[ti][1][r], v2 = S[ti][2][r];
            float v3 = (c16 == 0) ? S[ti][3][r] : -1e30f;
            float mx = fmaxf(fmaxf(v0, v1), fmaxf(v2, v3));
#pragma unroll
            for (int mk = 1; mk < 16; mk <<= 1) mx = fmaxf(mx, __shfl_xor(mx, mk, 64));
            float p0 = __expf(v0 - mx), p1 = __expf(v1 - mx), p2 = __expf(v2 - mx);
            float p3 = (c16 == 0) ? __expf(v3 - mx) : 0.f;
            float sm = p0 + p1 + p2 + p3;
#pragma unroll
            for (int mk = 1; mk < 16; mk <<= 1) sm += __shfl_xor(sm, mk, 64);
            float inv = 1.f / sm;
            Ps[wv][row][c16]      = (f16)(p0 * inv);
            Ps[wv][row][16 + c16] = (f16)(p1 * inv);
            Ps[wv][row][32 + c16] = (f16)(p2 * inv);
            Ps[wv][row][48 + c16] = (f16)(p3 * inv);
        }
    __syncthreads();

    // O^T = V^T P^T via mfma(vf, pf): lane col = q-token, rows = 4 consecutive d
    f32x4 O2[2][4];
    const f32x4 zf = (f32x4){0.f, 0.f, 0.f, 0.f};
#pragma unroll
    for (int td = 0; td < 2; ++td)
#pragma unroll
        for (int ti = 0; ti < 4; ++ti) O2[td][ti] = zf;
#pragma unroll
    for (int c = 0; c < 2; ++c) {
        f16x8 pf[4], vf[2];
#pragma unroll
        for (int ti = 0; ti < 4; ++ti)
            pf[ti] = *(const f16x8*)&Ps[wv][ti * 16 + c16][c * 32 + g * 8];
        int tcol = c * 32 + g * 8;
#pragma unroll
        for (int td = 0; td < 2; ++td) {
            f16x8 vv = z8;
            if (tcol < VTS)
                vv = *(const f16x8*)(vt + vbase + (size_t)(td * 16 + c16) * VTS + tcol);
            vf[td] = vv;
        }
#pragma unroll
        for (int td = 0; td < 2; ++td)
#pragma unroll
            for (int ti = 0; ti < 4; ++ti)
                O2[td][ti] = __builtin_amdgcn_mfma_f32_16x16x32_f16(vf[td], pf[ti], O2[td][ti], 0, 0, 0);
    }

#pragma unroll
    for (int ti = 0; ti < 4; ++ti) {
        int tok = ti * 16 + c16;
        if (tok < NTOK) {
            size_t ob = ((size_t)(b * NTOK + tok)) * DIM + h * HD;
#pragma unroll
            for (int td = 0; td < 2; ++td) {
                f32x4 v = O2[td][ti];
                f16x4 o = { (f16)v[0], (f16)v[1], (f16)v[2], (f16)v[3] };
                *(f16x4*)(aout + ob + td * 16 + g * 4) = o;
            }
        }
    }
}

// ---------------- launcher ----------------
extern "C" void kernel_launch(void* const* d_in, const int* in_sizes, int n_in,
                              void* d_out, int out_size, void* d_ws, size_t ws_size,
                              hipStream_t stream) {
    const float* x      = (const float*)d_in[0];
    const float* mask   = (const float*)d_in[1];
    const float* rpb    = (const float*)d_in[2];
    const float* qkv_w  = (const float*)d_in[3];
    const float* qkv_b  = (const float*)d_in[4];
    const float* proj_w = (const float*)d_in[5];
    const float* proj_b = (const float*)d_in[6];
    float* out = (float*)d_out;

    char* ws = (char*)d_ws;
    size_t o = 0;
    f16* x16   = (f16*)(ws + o); o += (size_t)MTOT * DIM * 2;
    f16* w16   = (f16*)(ws + o); o += (size_t)1536 * 512 * 2;
    f16* pw16  = (f16*)(ws + o); o += (size_t)512 * 512 * 2;
    f16* qws   = (f16*)(ws + o); o += (size_t)NB * NH * NTOK * HD * 2;
    f16* kws   = (f16*)(ws + o); o += (size_t)NB * NH * NTOK * HD * 2;
    f16* vtws  = (f16*)(ws + o); o += (size_t)NB * NH * HD * VTS * 2;
    f16* cb2   = (f16*)(ws + o);
    f16* aout = x16;   // x16 dead after QKV GEMM

    cvt_f32_f16<<<dim3(2048), dim3(256), 0, stream>>>(x, x16, MTOT * DIM / 4);
    cvt_f32_f16<<<dim3(768), dim3(256), 0, stream>>>(qkv_w, w16, 1536 * 512 / 4);
    cvt_f32_f16<<<dim3(256), dim3(256), 0, stream>>>(proj_w, pw16, 512 * 512 / 4);

    build_comb2<<<dim3(16384), dim3(256), 0, stream>>>(rpb, mask, cb2);

    // QKV: 392 m-tiles x 6 n-tiles = 2352 blocks (divisible by 8)
    gemm_kernel<0, 6><<<dim3((MTOT / 256) * 6), dim3(512), 0, stream>>>(
        x16, w16, qkv_b, qws, kws, vtws, nullptr);

    attn_kernel<<<dim3(NB * NH / 4), dim3(256), 0, stream>>>(qws, kws, vtws, cb2, aout);

    // proj: 392 x 2 = 784 blocks (divisible by 8)
    gemm_kernel<1, 2><<<dim3((MTOT / 256) * 2), dim3(512), 0, stream>>>(
        aout, pw16, proj_b, nullptr, nullptr, nullptr, out);
}